// Round 17
// baseline (191.954 us; speedup 1.0000x reference)
//
#include <hip/hip_runtime.h>
#include <hip/hip_bf16.h>

#define BATCH 64
#define MDIM 512
#define NDIM 1024
#define KDIM 1024

#define BM 256
#define BN 256
#define BK 32               // fp32 K per tile (128 B = 8 x 16B granules/row)
#define NKT (KDIM / BK)     // 32 K-tiles

typedef __attribute__((ext_vector_type(4))) float f32x4;
typedef __attribute__((ext_vector_type(8))) short bf16x8;
typedef __attribute__((ext_vector_type(4))) unsigned int u32x4;

__device__ __forceinline__ unsigned int cvt2(float lo, float hi) {
    __hip_bfloat162 h = __float22bfloat162_rn(float2{lo, hi});
    return *(unsigned int*)&h;
}

#define MFMA16(a, b, c) __builtin_amdgcn_mfma_f32_16x16x32_bf16((a), (b), (c), 0, 0, 0)
#define SB0 __builtin_amdgcn_sched_barrier(0)
#define WAITLG(n) do { asm volatile("s_waitcnt lgkmcnt(" #n ")" ::: "memory"); SB0; } while (0)

__global__ __launch_bounds__(512, 2)
void grouped_fc_kernel(const float* __restrict__ X,
                       const float* __restrict__ W,
                       const float* __restrict__ Bias,
                       float* __restrict__ Out) {
    // XCD swizzle (bijective: 512 % 8 == 0)
    const int swz  = (blockIdx.x & 7) * 64 + (blockIdx.x >> 3);
    const int bidx = swz >> 3;
    const int tile = swz & 7;
    const int tm = tile & 1;
    const int tn = tile >> 1;

    const int tid  = threadIdx.x;
    const int lane = tid & 63;
    const int wid  = tid >> 6;
    const int wm   = wid & 1;      // 2 wave rows (128 out-rows)
    const int wn   = wid >> 1;     // 4 wave cols (64 out-cols)

    // fp32 tiles, [row][8 x 16B granules], DMA'd linear; swizzle lives in
    // the per-lane GLOBAL source address (R12-proven correct):
    //   LDS[r][p] = global[r][p ^ (r&7)]
    // Reads at p = (2khi+d)^(r&7) are conflict-free per 8-lane group.
    __shared__ float ldsA[2][BM][BK];
    __shared__ float ldsB[2][BN][BK];

    const float* srcA = X + ((size_t)bidx * MDIM + (size_t)tm * BM) * KDIM;
    const float* srcB = W + ((size_t)bidx * NDIM + (size_t)tn * BN) * KDIM;

    // DMA geometry: one instr = 64 lanes x 16B = 1 KB = 8 fp32 rows.
    const int lrow = lane >> 3;              // row within 8-row chunk
    const int lgr  = (lane & 7) ^ lrow;      // pre-swizzled source granule
    const size_t lsrc = (size_t)lrow * KDIM + lgr * 4;

    auto STAGE = [&](int buf, int kt) {      // 8 wave-level gload_lds
#pragma unroll
        for (int j = 0; j < 4; ++j) {
            const int c = wid * 4 + j;       // chunk 0..31
            const float* ga = srcA + (size_t)c * 8 * KDIM + kt * BK + lsrc;
            __builtin_amdgcn_global_load_lds(
                (const __attribute__((address_space(1))) void*)ga,
                (__attribute__((address_space(3))) void*)&ldsA[buf][c * 8][0],
                16, 0, 0);
        }
#pragma unroll
        for (int j = 0; j < 4; ++j) {
            const int c = wid * 4 + j;
            const float* gb = srcB + (size_t)c * 8 * KDIM + kt * BK + lsrc;
            __builtin_amdgcn_global_load_lds(
                (const __attribute__((address_space(1))) void*)gb,
                (__attribute__((address_space(3))) void*)&ldsB[buf][c * 8][0],
                16, 0, 0);
        }
    };

    // frag read: lane (frow,khi) needs K fp32 [khi*8, +8) = granules
    // {2khi, 2khi+1} stored at {(2khi)^(r&7), ^1}. r&7 == frow&7.
    const int frow = lane & 15;
    const int khi  = lane >> 4;
    const int s0   = (((khi * 2) ^ (frow & 7))) * 4;  // fp32 offset of lo

    auto CVT = [&](const f32x4& lo, const f32x4& hi) -> bf16x8 {
        u32x4 u;
        u[0] = cvt2(lo[0], lo[1]); u[1] = cvt2(lo[2], lo[3]);
        u[2] = cvt2(hi[0], hi[1]); u[3] = cvt2(hi[2], hi[3]);
        return __builtin_bit_cast(bf16x8, u);
    };

    f32x4 acc[8][4];
#pragma unroll
    for (int mi = 0; mi < 8; ++mi)
#pragma unroll
        for (int ni = 0; ni < 4; ++ni)
            acc[mi][ni] = (f32x4){0.f, 0.f, 0.f, 0.f};

    // prologue: DMA tile 0 -> buf0
    STAGE(0, 0);
    asm volatile("s_waitcnt vmcnt(0)" ::: "memory");
    SB0;
    __builtin_amdgcn_s_barrier();
    SB0;

#pragma unroll 1
    for (int kt = 0; kt < NKT; ++kt) {
        const int rd = kt & 1;
        const bool m1 = (kt + 1 < NKT);

        if (m1) STAGE(rd ^ 1, kt + 1);   // flight = whole tile body

        const float* pa[8];
        const float* pb[4];
#pragma unroll
        for (int mi = 0; mi < 8; ++mi) pa[mi] = &ldsA[rd][wm * 128 + mi * 16 + frow][0];
#pragma unroll
        for (int ni = 0; ni < 4; ++ni) pb[ni] = &ldsB[rd][wn * 64 + ni * 16 + frow][0];

        // ---- G0: B0-3 + A0-1 (12 reads) ; G1: A2-4 (6 reads) issued deep
        f32x4 bl[4], bh[4], al0[2], ah0[2], al1[3], ah1[3];
#pragma unroll
        for (int ni = 0; ni < 4; ++ni) {
            bl[ni] = *(const f32x4*)(pb[ni] + s0);
            bh[ni] = *(const f32x4*)(pb[ni] + (s0 ^ 4));
        }
#pragma unroll
        for (int g = 0; g < 2; ++g) {
            al0[g] = *(const f32x4*)(pa[g] + s0);
            ah0[g] = *(const f32x4*)(pa[g] + (s0 ^ 4));
        }
#pragma unroll
        for (int g = 0; g < 3; ++g) {
            al1[g] = *(const f32x4*)(pa[2 + g] + s0);
            ah1[g] = *(const f32x4*)(pa[2 + g] + (s0 ^ 4));
        }
        WAITLG(6);                        // G0's 12 done; G1's 6 in flight
        bf16x8 bfr[4], af[8];
#pragma unroll
        for (int ni = 0; ni < 4; ++ni) bfr[ni] = CVT(bl[ni], bh[ni]);
        af[0] = CVT(al0[0], ah0[0]);
        af[1] = CVT(al0[1], ah0[1]);
        __builtin_amdgcn_s_setprio(1);
#pragma unroll
        for (int mi = 0; mi < 2; ++mi)
#pragma unroll
            for (int ni = 0; ni < 4; ++ni)
                acc[mi][ni] = MFMA16(af[mi], bfr[ni], acc[mi][ni]);
        __builtin_amdgcn_s_setprio(0);
        SB0;

        // ---- G2: A5-7 (6 reads) issued under G1's MFMA
        f32x4 al2[3], ah2[3];
#pragma unroll
        for (int g = 0; g < 3; ++g) {
            al2[g] = *(const f32x4*)(pa[5 + g] + s0);
            ah2[g] = *(const f32x4*)(pa[5 + g] + (s0 ^ 4));
        }
        WAITLG(6);                        // G1 done; G2 in flight
#pragma unroll
        for (int g = 0; g < 3; ++g) af[2 + g] = CVT(al1[g], ah1[g]);
        __builtin_amdgcn_s_setprio(1);
#pragma unroll
        for (int mi = 2; mi < 5; ++mi)
#pragma unroll
            for (int ni = 0; ni < 4; ++ni)
                acc[mi][ni] = MFMA16(af[mi], bfr[ni], acc[mi][ni]);
        __builtin_amdgcn_s_setprio(0);
        SB0;

        WAITLG(0);                        // G2 done
#pragma unroll
        for (int g = 0; g < 3; ++g) af[5 + g] = CVT(al2[g], ah2[g]);
        __builtin_amdgcn_s_setprio(1);
#pragma unroll
        for (int mi = 5; mi < 8; ++mi)
#pragma unroll
            for (int ni = 0; ni < 4; ++ni)
                acc[mi][ni] = MFMA16(af[mi], bfr[ni], acc[mi][ni]);
        __builtin_amdgcn_s_setprio(0);

        // seal: next-tile DMA landed (cheap: flight >> HBM latency);
        // our ds_reads all consumed above.
        asm volatile("s_waitcnt vmcnt(0)" ::: "memory");
        SB0;
        __builtin_amdgcn_s_barrier();
        SB0;
    }

    // epilogue: acc layout col=lane&15, row=(lane>>4)*4+r (m89-verified)
#pragma unroll
    for (int ni = 0; ni < 4; ++ni) {
        const int gc = tn * BN + wn * 64 + ni * 16 + frow;
        const float bv = Bias[bidx * NDIM + gc];
#pragma unroll
        for (int mi = 0; mi < 8; ++mi) {
            const int gr0 = tm * BM + wm * 128 + mi * 16 + khi * 4;
            float* po = Out + ((size_t)bidx * MDIM + gr0) * NDIM + gc;
#pragma unroll
            for (int r = 0; r < 4; ++r)
                po[(size_t)r * NDIM] = acc[mi][ni][r] + bv;
        }
    }
}

extern "C" void kernel_launch(void* const* d_in, const int* in_sizes, int n_in,
                              void* d_out, int out_size, void* d_ws, size_t ws_size,
                              hipStream_t stream) {
    const float* X  = (const float*)d_in[0];
    const float* W  = (const float*)d_in[1];
    const float* Bs = (const float*)d_in[2];
    float* Out = (float*)d_out;

    grouped_fc_kernel<<<dim3(512), dim3(512), 0, stream>>>(X, W, Bs, Out);
}

// Round 18
// 161.214 us; speedup vs baseline: 1.1907x; 1.1907x over previous
//
#include <hip/hip_runtime.h>
#include <hip/hip_bf16.h>

#define BATCH 64
#define MDIM 512
#define NDIM 1024
#define KDIM 1024

#define BM 256
#define BN 256
#define BK 64
#define NKT (KDIM / BK)     // 16 K-tiles

typedef __attribute__((ext_vector_type(4))) float f32x4;
typedef __attribute__((ext_vector_type(8))) short bf16x8;
typedef __attribute__((ext_vector_type(4))) unsigned int u32x4;

__device__ __forceinline__ unsigned int cvt2(float lo, float hi) {
    __hip_bfloat162 h = __float22bfloat162_rn(float2{lo, hi});
    return *(unsigned int*)&h;
}

#define MFMA16(a, b, c) __builtin_amdgcn_mfma_f32_16x16x32_bf16((a), (b), (c), 0, 0, 0)
#define SB0 __builtin_amdgcn_sched_barrier(0)
#define WAITLG(n) do { asm volatile("s_waitcnt lgkmcnt(" #n ")" ::: "memory"); SB0; } while (0)
#define BAR do { SB0; __builtin_amdgcn_s_barrier(); SB0; } while (0)

__global__ __launch_bounds__(512, 2)
void grouped_fc_kernel(const float* __restrict__ X,
                       const float* __restrict__ W,
                       const float* __restrict__ Bias,
                       float* __restrict__ Out) {
    // XCD swizzle (bijective: 512 % 8 == 0)
    const int swz  = (blockIdx.x & 7) * 64 + (blockIdx.x >> 3);
    const int bidx = swz >> 3;
    const int tile = swz & 7;
    const int tm = tile & 1;
    const int tn = tile >> 1;

    const int tid  = threadIdx.x;
    const int lane = tid & 63;
    const int wid  = tid >> 6;
    const int wm   = wid & 1;      // 2 wave rows (128 out-rows)
    const int wn   = wid >> 1;     // 4 wave cols (64 out-cols)

    // [row][64] bf16 = 8 x 16B slots/row; slot s at s ^ (row&7).
    // R9/R13-verified: SQ_LDS_BANK_CONFLICT == 0.
    __shared__ unsigned short ldsA[2][BM][BK];
    __shared__ unsigned short ldsB[2][BN][BK];

    const float* srcA = X + ((size_t)bidx * MDIM + (size_t)tm * BM) * KDIM;
    const float* srcB = W + ((size_t)bidx * NDIM + (size_t)tn * BN) * KDIM;

    // staging: 4 threads/row, 16 fp32 each, per 128-row half-tile
    const int s_r  = tid >> 2;
    const int s_cf = (tid & 3) * 16;
    const int s_x  = s_r & 7;
    const int so0  = (((tid & 3) * 2)     ^ s_x) * 8;
    const int so1  = (((tid & 3) * 2 + 1) ^ s_x) * 8;

    // 4 independent staging sets: A-h0, A-h1, B-h0, B-h1 of tile kt+1,
    // ALL issued at tile start -> no mid-tile WAR chains.
    f32x4 sa0[4], sa1[4], sb0[4], sb1[4];

    auto ISSUE1 = [&](const float* srcbase, int hv, int kt_, f32x4 (&s)[4]) {
        const float* p = srcbase + (size_t)(hv * 128 + s_r) * KDIM + kt_ * BK + s_cf;
#pragma unroll
        for (int v = 0; v < 4; ++v) s[v] = *(const f32x4*)(p + v * 4);
    };

    auto CVTW = [&](unsigned short* ldsbase, int hv, f32x4 (&s)[4]) {
        const int row = hv * 128 + s_r;
        u32x4 w0, w1;
        w0[0] = cvt2(s[0][0], s[0][1]); w0[1] = cvt2(s[0][2], s[0][3]);
        w0[2] = cvt2(s[1][0], s[1][1]); w0[3] = cvt2(s[1][2], s[1][3]);
        w1[0] = cvt2(s[2][0], s[2][1]); w1[1] = cvt2(s[2][2], s[2][3]);
        w1[2] = cvt2(s[3][0], s[3][1]); w1[3] = cvt2(s[3][2], s[3][3]);
        *(u32x4*)&ldsbase[(size_t)row * BK + so0] = w0;
        *(u32x4*)&ldsbase[(size_t)row * BK + so1] = w1;
    };

    // frag reads: row&7 == frow&7 (frag base rows are multiples of 8)
    const int frow = lane & 15;
    const int khi  = lane >> 4;
    const int xr   = frow & 7;
    const int oK0  = ((khi)     ^ xr) * 8;
    const int oK1  = ((4 + khi) ^ xr) * 8;

    auto rdA = [&](int buf, int mi, int o) {
        return *(const bf16x8*)&ldsA[buf][wm * 128 + mi * 16 + frow][o];
    };
    auto rdB = [&](int buf, int ni, int o) {
        return *(const bf16x8*)&ldsB[buf][wn * 64 + ni * 16 + frow][o];
    };

    f32x4 acc[8][4];
#pragma unroll
    for (int mi = 0; mi < 8; ++mi)
#pragma unroll
        for (int ni = 0; ni < 4; ++ni)
            acc[mi][ni] = (f32x4){0.f, 0.f, 0.f, 0.f};

    // ---- prologue: stage tile 0 -> buf0, seal ----
    ISSUE1(srcA, 0, 0, sa0); ISSUE1(srcA, 1, 0, sa1);
    ISSUE1(srcB, 0, 0, sb0); ISSUE1(srcB, 1, 0, sb1);
    CVTW(&ldsA[0][0][0], 0, sa0); CVTW(&ldsA[0][0][0], 1, sa1);
    CVTW(&ldsB[0][0][0], 0, sb0); CVTW(&ldsB[0][0][0], 1, sb1);
    WAITLG(0);
    BAR;

    bf16x8 af[8], bfr[4];

    // main loop over tiles 0..NKT-2: one barrier per tile.
    // DS queue per tile: [r12(ks0)] wait0 | [r12(ks1)] [w4(A)] wait4 |
    // [w4(B)] wait0 BAR.  Reads always issued before writes (SB0-pinned)
    // so counted waits are exact.
#pragma unroll 1
    for (int kt = 0; kt < NKT - 1; ++kt) {
        const int rd = kt & 1;
        unsigned short* nA = &ldsA[rd ^ 1][0][0];
        unsigned short* nB = &ldsB[rd ^ 1][0][0];

        // issue ALL of tile kt+1 (16 loads); consumed at mid/end of this tile
        ISSUE1(srcA, 0, kt + 1, sa0); ISSUE1(srcA, 1, kt + 1, sa1);
        ISSUE1(srcB, 0, kt + 1, sb0); ISSUE1(srcB, 1, kt + 1, sb1);
        SB0;

        // ---- ks0: reads + MFMA ----
#pragma unroll
        for (int mi = 0; mi < 8; ++mi) af[mi] = rdA(rd, mi, oK0);
#pragma unroll
        for (int ni = 0; ni < 4; ++ni) bfr[ni] = rdB(rd, ni, oK0);
        WAITLG(0);                       // queue was empty; 12 reads done
        __builtin_amdgcn_s_setprio(1);
#pragma unroll
        for (int mi = 0; mi < 8; ++mi)
#pragma unroll
            for (int ni = 0; ni < 4; ++ni)
                acc[mi][ni] = MFMA16(af[mi], bfr[ni], acc[mi][ni]);
        __builtin_amdgcn_s_setprio(0);
        SB0;

        // ---- ks1 reads first, then A-writes (order pinned) ----
#pragma unroll
        for (int mi = 0; mi < 8; ++mi) af[mi] = rdA(rd, mi, oK1);
#pragma unroll
        for (int ni = 0; ni < 4; ++ni) bfr[ni] = rdB(rd, ni, oK1);
        SB0;
        CVTW(nA, 0, sa0); CVTW(nA, 1, sa1);   // 4 writes (vmcnt: ~half-tile flight)
        WAITLG(4);                       // 12 reads done; 4 A-writes pending
        __builtin_amdgcn_s_setprio(1);
#pragma unroll
        for (int mi = 0; mi < 8; ++mi)
#pragma unroll
            for (int ni = 0; ni < 4; ++ni)
                acc[mi][ni] = MFMA16(af[mi], bfr[ni], acc[mi][ni]);
        __builtin_amdgcn_s_setprio(0);
        SB0;

        // ---- B-writes + tile seal ----
        CVTW(nB, 0, sb0); CVTW(nB, 1, sb1);   // 4 writes
        WAITLG(0);                       // all writes drained
        BAR;                             // buf^1 sealed; reads of rd consumed
    }

    // ---- peeled last tile (no staging) ----
    {
        const int rd = (NKT - 1) & 1;
#pragma unroll
        for (int mi = 0; mi < 8; ++mi) af[mi] = rdA(rd, mi, oK0);
#pragma unroll
        for (int ni = 0; ni < 4; ++ni) bfr[ni] = rdB(rd, ni, oK0);
        WAITLG(0);
#pragma unroll
        for (int mi = 0; mi < 8; ++mi)
#pragma unroll
            for (int ni = 0; ni < 4; ++ni)
                acc[mi][ni] = MFMA16(af[mi], bfr[ni], acc[mi][ni]);
#pragma unroll
        for (int mi = 0; mi < 8; ++mi) af[mi] = rdA(rd, mi, oK1);
#pragma unroll
        for (int ni = 0; ni < 4; ++ni) bfr[ni] = rdB(rd, ni, oK1);
        WAITLG(0);
#pragma unroll
        for (int mi = 0; mi < 8; ++mi)
#pragma unroll
            for (int ni = 0; ni < 4; ++ni)
                acc[mi][ni] = MFMA16(af[mi], bfr[ni], acc[mi][ni]);
    }

    // epilogue: acc layout col=lane&15, row=(lane>>4)*4+r (m89-verified)
#pragma unroll
    for (int ni = 0; ni < 4; ++ni) {
        const int gc = tn * BN + wn * 64 + ni * 16 + frow;
        const float bv = Bias[bidx * NDIM + gc];
#pragma unroll
        for (int mi = 0; mi < 8; ++mi) {
            const int gr0 = tm * BM + wm * 128 + mi * 16 + khi * 4;
            float* po = Out + ((size_t)bidx * MDIM + gr0) * NDIM + gc;
#pragma unroll
            for (int r = 0; r < 4; ++r)
                po[(size_t)r * NDIM] = acc[mi][ni][r] + bv;
        }
    }
}

extern "C" void kernel_launch(void* const* d_in, const int* in_sizes, int n_in,
                              void* d_out, int out_size, void* d_ws, size_t ws_size,
                              hipStream_t stream) {
    const float* X  = (const float*)d_in[0];
    const float* W  = (const float*)d_in[1];
    const float* Bs = (const float*)d_in[2];
    float* Out = (float*)d_out;

    grouped_fc_kernel<<<dim3(512), dim3(512), 0, stream>>>(X, W, Bs, Out);
}